// Round 14
// baseline (61.074 us; speedup 1.0000x reference)
//
#include <hip/hip_runtime.h>
#include <stdint.h>

#define LSEQ 1024
#define EDIM 32
#define NDIM 64

typedef __attribute__((ext_vector_type(8))) short short8;
typedef __attribute__((ext_vector_type(4))) float f32x4;

static __device__ __forceinline__ unsigned short f2bf(float f) {
    unsigned int u = __float_as_uint(f);
    u += 0x7FFFu + ((u >> 16) & 1u);
    return (unsigned short)(u >> 16);
}

// async global->LDS, 16B per lane: dest = wave-uniform base + lane*16
static __device__ __forceinline__ void gll16(const float* g, float* l) {
    __builtin_amdgcn_global_load_lds(
        (const __attribute__((address_space(1))) void*)g,
        (__attribute__((address_space(3))) void*)l, 16, 0, 0);
}
static __device__ __forceinline__ uint32_t ldsoff(const void* p) {
    return (uint32_t)(uintptr_t)(const __attribute__((address_space(3))) void*)p;
}

// Kernel A: niB = node@Wi + b_pair, njB = node@Wj (f32); wpT = (Wp + I)^T in bf16
__global__ __launch_bounds__(256) void evo_pre(
    const float* __restrict__ node,   // [1024][64]
    const float* __restrict__ Wpair,  // [160][32]
    const float* __restrict__ bpair,  // [32]
    float* __restrict__ niB,          // [1024][32]
    float* __restrict__ njB,          // [1024][32]
    unsigned short* __restrict__ wpT) // [32][32] bf16, row f, col e
{
    int g = blockIdx.x * 256 + threadIdx.x;
    if (g < LSEQ * EDIM) {
        int i = g >> 5, f = g & 31;
        float acci = bpair[f];
        float accj = 0.0f;
        const float* nrow = node + i * NDIM;
        #pragma unroll
        for (int k = 0; k < NDIM; ++k) {
            float nv = nrow[k];
            acci += nv * Wpair[k * 32 + f];
            accj += nv * Wpair[(64 + k) * 32 + f];
        }
        niB[g] = acci;
        njB[g] = accj;
    } else {
        int idx = g - LSEQ * EDIM;
        if (idx < EDIM * EDIM) {
            int f = idx >> 5, e = idx & 31;
            float v = Wpair[(128 + e) * 32 + f];
            if (e == f) v += 1.0f;  // fold the +pair residual into the matmul
            wpT[f * 32 + e] = f2bf(v);
        }
    }
}

// Kernel B: 2048 blocks = 2 per row i; block (4 waves) owns 512 j's, wave 128.
// T3/T4: pair+nj tiles DMA'd via global_load_lds into per-wave double-buffered
// LDS slots; consumed with inline-asm ds_read_b128 under counted vmcnt (never 0
// in steady state). Pair DMA source pre-swizzled so linear LDS dest gives
// conflict-free frag reads. Out-stage (R9) unchanged.
__global__ __launch_bounds__(256, 3) void evo_main(
    const float* __restrict__ pair,   // [1024][1024][32]
    const float* __restrict__ niB,    // [1024][32]
    const float* __restrict__ njB,    // [1024][32]
    const unsigned short* __restrict__ wpT,  // [32][32] bf16
    float* __restrict__ partial,      // [2048][32]
    float* __restrict__ out_pair)     // [1024][1024][32]
{
    __shared__ float pslot[4][2][512];  // pair tiles: 4 waves x 2 slots x 2KB
    __shared__ float nslot[4][2][512];  // nj tiles
    __shared__ float stage[4][512];     // out-stage (R9 layout)
    __shared__ float red[4][32];

    const int blk  = blockIdx.x;
    const int i    = blk >> 1;
    const int h    = blk & 1;
    const int tid  = threadIdx.x;
    const int wave = tid >> 6;
    const int lane = tid & 63;
    const int c    = lane & 15;   // frag: j-col select
    const int a    = lane >> 4;   // frag: k-chunk select
    const int q    = lane & 7;    // dense: 16-B chunk in row
    const int r0   = lane >> 3;   // dense: row in half-tile

    const short8 af0 = *(const short8*)(wpT + c * 32 + a * 8);
    const short8 af1 = *(const short8*)(wpT + (c + 16) * 32 + a * 8);
    const f32x4 ni_d = *(const f32x4*)(niB + i * 32 + q * 4);

    const int jw = (h << 9) + (wave << 7);
    const size_t tb = ((size_t)i * 1024 + (size_t)jw) * 32;

    // DMA sources (per-lane). pair: pre-swizzled chunk q^(r0&7); nj: identity.
    const float* psrc = pair + tb + r0 * 32 + (q ^ (r0 & 7)) * 4;
    const float* nsrc = njB + (size_t)(jw + r0) * 32 + q * 4;
    float*       preg = out_pair + tb + lane * 4;

    // frag-read float offsets within a pair slot (swizzle-matched)
    const int fi0 = c * 32 + (((2 * a)     ^ (c & 7)) << 2);
    const int fi1 = c * 32 + (((2 * a + 1) ^ (c & 7)) << 2);

    // out-stage addresses (R9 pattern; 0 conflicts measured)
    const int key = (c & 7) << 2;
    float* wr0 = &stage[wave][c * 32 + ((4 * a) ^ key)];
    float* wr1 = &stage[wave][c * 32 + ((16 + 4 * a) ^ key)];
    const float* rd0 = &stage[wave][r0 * 32 + ((q * 4) ^ ((r0 & 7) << 2))];
    const float* rd1 = rd0 + 256;

    const uint32_t pb0 = ldsoff(&pslot[wave][0][0]);
    const uint32_t pb1 = ldsoff(&pslot[wave][1][0]);
    const uint32_t nb0 = ldsoff(&nslot[wave][0][0]);
    const uint32_t nb1 = ldsoff(&nslot[wave][1][0]);

    f32x4 sumd = {0.f, 0.f, 0.f, 0.f};

    // prologue: DMA tiles 0 and 1 (4 ops each)
    __builtin_amdgcn_sched_barrier(0);
    gll16(psrc,       &pslot[wave][0][0]);
    gll16(psrc + 256, &pslot[wave][0][256]);
    gll16(nsrc,       &nslot[wave][0][0]);
    gll16(nsrc + 256, &nslot[wave][0][256]);
    __builtin_amdgcn_sched_barrier(0);
    gll16(psrc + 512, &pslot[wave][1][0]);
    gll16(psrc + 768, &pslot[wave][1][256]);
    gll16(nsrc + 512, &nslot[wave][1][0]);
    gll16(nsrc + 768, &nslot[wave][1][256]);

    #pragma unroll
    for (int t = 0; t < 8; ++t) {
        // wait for tile t: 6 vmem ops issued per later iter (2 stores + 4 DMA)
        if (t == 0)      asm volatile("s_waitcnt vmcnt(4)" ::: "memory");
        else if (t == 7) asm volatile("s_waitcnt vmcnt(2)" ::: "memory");
        else             asm volatile("s_waitcnt vmcnt(6)" ::: "memory");
        __builtin_amdgcn_sched_barrier(0);

        const uint32_t pb = (t & 1) ? pb1 : pb0;
        const uint32_t nb = (t & 1) ? nb1 : nb0;
        f32x4 b0, b1, j0, j1;
        asm volatile("ds_read_b128 %0, %1" : "=v"(b0) : "v"(pb + fi0 * 4));
        asm volatile("ds_read_b128 %0, %1" : "=v"(b1) : "v"(pb + fi1 * 4));
        asm volatile("ds_read_b128 %0, %1" : "=v"(j0) : "v"(nb + lane * 16));
        asm volatile("ds_read_b128 %0, %1" : "=v"(j1) : "v"(nb + lane * 16 + 1024));
        asm volatile("s_waitcnt lgkmcnt(0)" ::: "memory");
        __builtin_amdgcn_sched_barrier(0);

        short8 bfrag;
        bfrag[0] = (short)f2bf(b0.x); bfrag[1] = (short)f2bf(b0.y);
        bfrag[2] = (short)f2bf(b0.z); bfrag[3] = (short)f2bf(b0.w);
        bfrag[4] = (short)f2bf(b1.x); bfrag[5] = (short)f2bf(b1.y);
        bfrag[6] = (short)f2bf(b1.z); bfrag[7] = (short)f2bf(b1.w);
        const f32x4 z = {0.f, 0.f, 0.f, 0.f};
        const f32x4 acc0 = __builtin_amdgcn_mfma_f32_16x16x32_bf16(af0, bfrag, z, 0, 0, 0);
        const f32x4 acc1 = __builtin_amdgcn_mfma_f32_16x16x32_bf16(af1, bfrag, z, 0, 0, 0);

        // frag -> out-stage -> dense (+ni+nj), dense store
        *(f32x4*)wr0 = acc0;
        *(f32x4*)wr1 = acc1;
        const f32x4 d0 = *(const f32x4*)rd0 + ni_d + j0;
        const f32x4 d1 = *(const f32x4*)rd1 + ni_d + j1;
        sumd += d0 + d1;
        *(f32x4*)(preg + t * 512)       = d0;
        *(f32x4*)(preg + t * 512 + 256) = d1;

        // refill slot t&1 with tile t+2 (slot fully consumed: lgkm drained above)
        if (t < 6) {
            asm volatile("s_waitcnt lgkmcnt(0)" ::: "memory");
            __builtin_amdgcn_sched_barrier(0);
            float* pd = (t & 1) ? &pslot[wave][1][0] : &pslot[wave][0][0];
            float* nd = (t & 1) ? &nslot[wave][1][0] : &nslot[wave][0][0];
            gll16(psrc + (t + 2) * 512,       pd);
            gll16(psrc + (t + 2) * 512 + 256, pd + 256);
            gll16(nsrc + (t + 2) * 512,       nd);
            gll16(nsrc + (t + 2) * 512 + 256, nd + 256);
        }
    }

    // dense j-sum reduce: lanes sharing q (bits 3..5 vary) hold disjoint rows
    for (int m = 8; m < 64; m <<= 1) {
        sumd.x += __shfl_xor(sumd.x, m);
        sumd.y += __shfl_xor(sumd.y, m);
        sumd.z += __shfl_xor(sumd.z, m);
        sumd.w += __shfl_xor(sumd.w, m);
    }
    if (lane < 8) *(f32x4*)&red[wave][q * 4] = sumd;
    __syncthreads();
    if (tid < 32) {
        partial[blk * 32 + tid] = red[0][tid] + red[1][tid] + red[2][tid] + red[3][tid];
    }
}

// Kernel C: node update + LayerNorm. One block (1 wave) per row i.
__global__ __launch_bounds__(64) void evo_finish(
    const float* __restrict__ node,     // [1024][64]
    const float* __restrict__ partial,  // [2048][32]
    const float* __restrict__ Wnode,    // [96][64]
    const float* __restrict__ bnode,    // [64]
    const float* __restrict__ lnsc,     // [64]
    const float* __restrict__ lnof,     // [64]
    float* __restrict__ out_node)       // [1024][64]
{
    __shared__ float node_f[64];
    __shared__ float p2n[32];
    const int i   = blockIdx.x;
    const int tid = threadIdx.x;

    node_f[tid] = node[i * 64 + tid];
    if (tid < 32) {
        p2n[tid] = (partial[(2 * i) * 32 + tid] + partial[(2 * i + 1) * 32 + tid])
                   * (1.0f / 1024.0f);
    }
    __syncthreads();

    float acc = node_f[tid] + bnode[tid];
    #pragma unroll 8
    for (int k = 0; k < 64; ++k)
        acc += node_f[k] * Wnode[k * 64 + tid];
    #pragma unroll 8
    for (int k = 0; k < 32; ++k)
        acc += p2n[k] * Wnode[(64 + k) * 64 + tid];

    float s = acc, s2 = acc * acc;
    for (int m = 1; m < 64; m <<= 1) {
        s  += __shfl_xor(s, m);
        s2 += __shfl_xor(s2, m);
    }
    const float mean = s * (1.0f / 64.0f);
    const float var  = s2 * (1.0f / 64.0f) - mean * mean;
    const float y = (acc - mean) * rsqrtf(var + 1e-5f) * lnsc[tid] + lnof[tid];
    out_node[i * 64 + tid] = y;
}

extern "C" void kernel_launch(void* const* d_in, const int* in_sizes, int n_in,
                              void* d_out, int out_size, void* d_ws, size_t ws_size,
                              hipStream_t stream) {
    const float* node  = (const float*)d_in[0];
    const float* pair  = (const float*)d_in[1];
    const float* Wpair = (const float*)d_in[2];
    const float* bpair = (const float*)d_in[3];
    const float* Wnode = (const float*)d_in[4];
    const float* bnode = (const float*)d_in[5];
    const float* lnsc  = (const float*)d_in[6];
    const float* lnof  = (const float*)d_in[7];

    float* niB = (float*)d_ws;                        // [1024][32] f32
    float* njB = niB + LSEQ * EDIM;                   // [1024][32] f32
    unsigned short* wpT = (unsigned short*)(njB + LSEQ * EDIM);  // [32][32] bf16 (2 KB)
    float* partial = (float*)(wpT + EDIM * EDIM);     // [2048][32] f32 (256 KB)

    float* out_node = (float*)d_out;
    float* out_pair = out_node + LSEQ * NDIM;

    evo_pre<<<132, 256, 0, stream>>>(node, Wpair, bpair, niB, njB, wpT);
    evo_main<<<2 * LSEQ, 256, 0, stream>>>(pair, niB, njB, wpT, partial, out_pair);
    evo_finish<<<LSEQ, 64, 0, stream>>>(node, partial, Wnode, bnode, lnsc, lnof,
                                        out_node);
}

// Round 15
// 55.252 us; speedup vs baseline: 1.1054x; 1.1054x over previous
//
#include <hip/hip_runtime.h>
#include <stdint.h>

#define LSEQ 1024
#define EDIM 32
#define NDIM 64

typedef __attribute__((ext_vector_type(8))) short short8;
typedef __attribute__((ext_vector_type(4))) float f32x4;

static __device__ __forceinline__ unsigned short f2bf(float f) {
    unsigned int u = __float_as_uint(f);
    u += 0x7FFFu + ((u >> 16) & 1u);
    return (unsigned short)(u >> 16);
}

// Kernel A: niB = node@Wi + b_pair, njB = node@Wj (f32); wpT = (Wp + I)^T in bf16
__global__ __launch_bounds__(256) void evo_pre(
    const float* __restrict__ node,   // [1024][64]
    const float* __restrict__ Wpair,  // [160][32]
    const float* __restrict__ bpair,  // [32]
    float* __restrict__ niB,          // [1024][32]
    float* __restrict__ njB,          // [1024][32]
    unsigned short* __restrict__ wpT) // [32][32] bf16, row f, col e
{
    int g = blockIdx.x * 256 + threadIdx.x;
    if (g < LSEQ * EDIM) {
        int i = g >> 5, f = g & 31;
        float acci = bpair[f];
        float accj = 0.0f;
        const float* nrow = node + i * NDIM;
        #pragma unroll
        for (int k = 0; k < NDIM; ++k) {
            float nv = nrow[k];
            acci += nv * Wpair[k * 32 + f];
            accj += nv * Wpair[(64 + k) * 32 + f];
        }
        niB[g] = acci;
        njB[g] = accj;
    } else {
        int idx = g - LSEQ * EDIM;
        if (idx < EDIM * EDIM) {
            int f = idx >> 5, e = idx & 31;
            float v = Wpair[(128 + e) * 32 + f];
            if (e == f) v += 1.0f;  // fold the +pair residual into the matmul
            wpT[f * 32 + e] = f2bf(v);
        }
    }
}

// Kernel B: 2048 blocks = 2 per row i; block (4 waves) owns 512 j's, wave 128.
// All global streams lane-ordered dense (1 KB contiguous per instruction).
// pair in -> dense load -> XOR-swizzled LDS in-tile -> frag ds_read -> MFMA
// MFMA out -> XOR-swizzled LDS out-stage -> dense read (+ni+nj) -> NT store
// (nt is safe here: every store instruction covers 8 FULL 128-B lines, unlike
//  R7's half-line fragment stores that caused RMW amplification under nt.)
__global__ __launch_bounds__(256, 4) void evo_main(
    const float* __restrict__ pair,   // [1024][1024][32]
    const float* __restrict__ niB,    // [1024][32]
    const float* __restrict__ njB,    // [1024][32]
    const unsigned short* __restrict__ wpT,  // [32][32] bf16
    float* __restrict__ partial,      // [2048][32]
    float* __restrict__ out_pair)     // [1024][1024][32]
{
    __shared__ float tin[4][512];     // per-wave 2-KB input tile (chunk-XOR layout)
    __shared__ float stage[4][512];   // per-wave 2-KB output stage (R9 layout)
    __shared__ float red[4][32];

    const int blk  = blockIdx.x;
    const int i    = blk >> 1;
    const int h    = blk & 1;
    const int tid  = threadIdx.x;
    const int wave = tid >> 6;
    const int lane = tid & 63;
    const int c    = lane & 15;   // frag: j-col select
    const int a    = lane >> 4;   // frag: k-chunk select
    const int q    = lane & 7;    // dense: 16-B chunk within row
    const int r0   = lane >> 3;   // dense: row within half-tile

    // A fragments (loop-invariant)
    const short8 af0 = *(const short8*)(wpT + c * 32 + a * 8);
    const short8 af1 = *(const short8*)(wpT + (c + 16) * 32 + a * 8);
    // ni bias, dense side: depends only on f-chunk q (loop-invariant)
    const f32x4 ni_d = *(const f32x4*)(niB + i * 32 + q * 4);

    const int jw = (h << 9) + (wave << 7);
    const size_t tb = ((size_t)i * 1024 + (size_t)jw) * 32;
    const float* pinD = pair + tb + lane * 4;                   // dense in
    const float* njD  = njB + (size_t)(jw + r0) * 32 + q * 4;   // dense nj
    float*       preg = out_pair + tb + lane * 4;               // dense out

    // LDS in-tile: write dense rows with 16-B chunk XOR; read frag pattern
    const int xin = (q ^ (r0 & 7)) * 4;
    float* inW0 = &tin[wave][r0 * 32 + xin];          // rows 0-7
    float* inW1 = inW0 + 256;                         // rows 8-15 (same key)
    const float* bf0p = &tin[wave][c * 32 + (((2 * a)     ^ (c & 7)) * 4)];
    const float* bf1p = &tin[wave][c * 32 + (((2 * a + 1) ^ (c & 7)) * 4)];

    // LDS out-stage (identical to R9; 0 bank conflicts measured)
    const int key = (c & 7) << 2;
    float* wr0 = &stage[wave][c * 32 + ((4 * a) ^ key)];
    float* wr1 = &stage[wave][c * 32 + ((16 + 4 * a) ^ key)];
    const float* rd0 = &stage[wave][r0 * 32 + ((q * 4) ^ ((r0 & 7) << 2))];
    const float* rd1 = rd0 + 256;

    // 1-deep double-buffered prefetch (pair + nj), static indices under unroll
    f32x4 P0[2], P1[2], J0[2], J1[2];
    P0[0] = *(const f32x4*)(pinD);
    P1[0] = *(const f32x4*)(pinD + 256);
    J0[0] = *(const f32x4*)(njD);
    J1[0] = *(const f32x4*)(njD + 256);

    f32x4 sumd = {0.f, 0.f, 0.f, 0.f};

    #pragma unroll
    for (int t = 0; t < 8; ++t) {
        const int cur = t & 1, nxt = cur ^ 1;
        if (t < 7) {
            P0[nxt] = *(const f32x4*)(pinD + (t + 1) * 512);
            P1[nxt] = *(const f32x4*)(pinD + (t + 1) * 512 + 256);
            J0[nxt] = *(const f32x4*)(njD + (t + 1) * 512);
            J1[nxt] = *(const f32x4*)(njD + (t + 1) * 512 + 256);
        }

        // dense regs -> swizzled LDS in-tile
        *(f32x4*)inW0 = P0[cur];
        *(f32x4*)inW1 = P1[cur];

        // frag read (conflict-free via XOR) + bf16 pack + MFMA
        const f32x4 b0 = *(const f32x4*)bf0p;
        const f32x4 b1 = *(const f32x4*)bf1p;
        short8 bfrag;
        bfrag[0] = (short)f2bf(b0.x); bfrag[1] = (short)f2bf(b0.y);
        bfrag[2] = (short)f2bf(b0.z); bfrag[3] = (short)f2bf(b0.w);
        bfrag[4] = (short)f2bf(b1.x); bfrag[5] = (short)f2bf(b1.y);
        bfrag[6] = (short)f2bf(b1.z); bfrag[7] = (short)f2bf(b1.w);
        const f32x4 z = {0.f, 0.f, 0.f, 0.f};
        const f32x4 acc0 = __builtin_amdgcn_mfma_f32_16x16x32_bf16(af0, bfrag, z, 0, 0, 0);
        const f32x4 acc1 = __builtin_amdgcn_mfma_f32_16x16x32_bf16(af1, bfrag, z, 0, 0, 0);

        // frag -> out-stage -> dense; bias on dense side; NT dense store
        *(f32x4*)wr0 = acc0;
        *(f32x4*)wr1 = acc1;
        const f32x4 d0 = *(const f32x4*)rd0 + ni_d + J0[cur];
        const f32x4 d1 = *(const f32x4*)rd1 + ni_d + J1[cur];
        sumd += d0 + d1;
        __builtin_nontemporal_store(d0, (f32x4*)(preg + t * 512));
        __builtin_nontemporal_store(d1, (f32x4*)(preg + t * 512 + 256));
    }

    // reduce j-sums over rows: lanes differing in bits 3..5 share f-chunk q
    for (int m = 8; m < 64; m <<= 1) {
        sumd.x += __shfl_xor(sumd.x, m);
        sumd.y += __shfl_xor(sumd.y, m);
        sumd.z += __shfl_xor(sumd.z, m);
        sumd.w += __shfl_xor(sumd.w, m);
    }
    if (lane < 8) *(f32x4*)&red[wave][q * 4] = sumd;
    __syncthreads();
    if (tid < 32) {
        partial[blk * 32 + tid] = red[0][tid] + red[1][tid] + red[2][tid] + red[3][tid];
    }
}

// Kernel C: node update + LayerNorm. One block (1 wave) per row i.
__global__ __launch_bounds__(64) void evo_finish(
    const float* __restrict__ node,     // [1024][64]
    const float* __restrict__ partial,  // [2048][32]
    const float* __restrict__ Wnode,    // [96][64]
    const float* __restrict__ bnode,    // [64]
    const float* __restrict__ lnsc,     // [64]
    const float* __restrict__ lnof,     // [64]
    float* __restrict__ out_node)       // [1024][64]
{
    __shared__ float node_f[64];
    __shared__ float p2n[32];
    const int i   = blockIdx.x;
    const int tid = threadIdx.x;

    node_f[tid] = node[i * 64 + tid];
    if (tid < 32) {
        p2n[tid] = (partial[(2 * i) * 32 + tid] + partial[(2 * i + 1) * 32 + tid])
                   * (1.0f / 1024.0f);
    }
    __syncthreads();

    float acc = node_f[tid] + bnode[tid];
    #pragma unroll 8
    for (int k = 0; k < 64; ++k)
        acc += node_f[k] * Wnode[k * 64 + tid];
    #pragma unroll 8
    for (int k = 0; k < 32; ++k)
        acc += p2n[k] * Wnode[(64 + k) * 64 + tid];

    float s = acc, s2 = acc * acc;
    for (int m = 1; m < 64; m <<= 1) {
        s  += __shfl_xor(s, m);
        s2 += __shfl_xor(s2, m);
    }
    const float mean = s * (1.0f / 64.0f);
    const float var  = s2 * (1.0f / 64.0f) - mean * mean;
    const float y = (acc - mean) * rsqrtf(var + 1e-5f) * lnsc[tid] + lnof[tid];
    out_node[i * 64 + tid] = y;
}

extern "C" void kernel_launch(void* const* d_in, const int* in_sizes, int n_in,
                              void* d_out, int out_size, void* d_ws, size_t ws_size,
                              hipStream_t stream) {
    const float* node  = (const float*)d_in[0];
    const float* pair  = (const float*)d_in[1];
    const float* Wpair = (const float*)d_in[2];
    const float* bpair = (const float*)d_in[3];
    const float* Wnode = (const float*)d_in[4];
    const float* bnode = (const float*)d_in[5];
    const float* lnsc  = (const float*)d_in[6];
    const float* lnof  = (const float*)d_in[7];

    float* niB = (float*)d_ws;                        // [1024][32] f32
    float* njB = niB + LSEQ * EDIM;                   // [1024][32] f32
    unsigned short* wpT = (unsigned short*)(njB + LSEQ * EDIM);  // [32][32] bf16 (2 KB)
    float* partial = (float*)(wpT + EDIM * EDIM);     // [2048][32] f32 (256 KB)

    float* out_node = (float*)d_out;
    float* out_pair = out_node + LSEQ * NDIM;

    evo_pre<<<132, 256, 0, stream>>>(node, Wpair, bpair, niB, njB, wpT);
    evo_main<<<2 * LSEQ, 256, 0, stream>>>(pair, niB, njB, wpT, partial, out_pair);
    evo_finish<<<LSEQ, 64, 0, stream>>>(node, partial, Wnode, bnode, lnsc, lnof,
                                        out_node);
}